// Round 3
// baseline (496.280 us; speedup 1.0000x reference)
//
#include <hip/hip_runtime.h>
#include <hip/hip_bf16.h>

#define BB 2
#define LL 512
#define DIM 128
#define KK 32
#define EPSF 1e-5f

// ---------------------------------------------------------------------------
// Kernel A: per (path, b, q) row:
//   path 0: out_mean[b,q,:] -> out_agg = mean@W_out+b_out -> go = out_agg@Wg_o
//   path 1: in_mean [b,q,:] -> in_agg  = mean@W_in +b_in  -> gi = in_agg @Wg_i
// grid = 2*B*L blocks, 128 threads. Results stored f32 in workspace.
// ---------------------------------------------------------------------------
__global__ __launch_bounds__(DIM) void agg_gemm_kernel(
    const float* __restrict__ pair,
    const float* __restrict__ W_out, const float* __restrict__ b_out,
    const float* __restrict__ W_in,  const float* __restrict__ b_in,
    const float* __restrict__ W_g,
    float* __restrict__ agg,    // [2][B*L][DIM]  (0=out_agg, 1=in_agg)
    float* __restrict__ gpart)  // [2][B*L][DIM]  (0=go,      1=gi)
{
    const int t    = threadIdx.x;
    const int bid  = blockIdx.x;          // [0, 2*B*L)
    const int path = bid >> 10;           // B*L = 1024
    const int r    = bid & 1023;          // b*L + q
    const int b    = r >> 9;              // L = 512
    const int q    = r & 511;

    __shared__ float sm[DIM];

    // ---- stage 0: mean over K sampled positions (idx[k] = (k*511)/31) ----
    const float* base;
    long stride;
    if (path == 0) {
        // out_mean[b,q,:] = mean_k pair[b, q, idx[k], :]
        base   = pair + ((long)(b * LL + q) * LL) * DIM + t;
        stride = DIM;
    } else {
        // in_mean[b,q,:]  = mean_k pair[b, idx[k], q, :]
        base   = pair + ((long)b * LL * LL) * DIM + (long)q * DIM + t;
        stride = (long)LL * DIM;
    }
    float acc = 0.f;
#pragma unroll
    for (int k = 0; k < KK; ++k) {
        const int jj = (k * (LL - 1)) / (KK - 1);   // exact floor(linspace)
        acc += base[(long)jj * stride];
    }
    sm[t] = acc * (1.0f / KK);
    __syncthreads();

    // ---- stage 1: agg = mean @ W + bias ----
    const float* W    = (path == 0) ? W_out : W_in;
    const float* bias = (path == 0) ? b_out : b_in;
    float a = bias[t];
#pragma unroll 8
    for (int k = 0; k < DIM; ++k)
        a += sm[k] * W[k * DIM + t];
    __syncthreads();              // everyone done reading sm before overwrite
    sm[t] = a;
    agg[(long)path * BB * LL * DIM + (long)r * DIM + t] = a;
    __syncthreads();

    // ---- stage 2: gpart = agg @ Wg_path (b_g added elementwise later) ----
    const float* Wg = W_g + path * DIM * DIM;
    float g = 0.f;
#pragma unroll 8
    for (int k = 0; k < DIM; ++k)
        g += sm[k] * Wg[k * DIM + t];
    gpart[(long)path * BB * LL * DIM + (long)r * DIM + t] = g;
}

// ---------------------------------------------------------------------------
// Kernel B: gate/blend + LayerNorm over DIM=128.
// 16 lanes per row x 8 elems/lane; f32 in and f32 out (2x float4/lane each).
// 256 threads = 16 rows/block.
// ---------------------------------------------------------------------------
__device__ __forceinline__ void load8(const float* p, float* f) {
    const float4 a = reinterpret_cast<const float4*>(p)[0];
    const float4 b = reinterpret_cast<const float4*>(p)[1];
    f[0] = a.x; f[1] = a.y; f[2] = a.z; f[3] = a.w;
    f[4] = b.x; f[5] = b.y; f[6] = b.z; f[7] = b.w;
}

__global__ __launch_bounds__(256) void fuse_ln_kernel(
    const float* __restrict__ pair,
    const float* __restrict__ out_agg, const float* __restrict__ in_agg,
    const float* __restrict__ go,      const float* __restrict__ gi,
    const float* __restrict__ b_g, const float* __restrict__ ln_w,
    const float* __restrict__ ln_b,
    float* __restrict__ out)
{
    const int  tid    = threadIdx.x;
    const int  lane16 = tid & 15;
    const int  rloc   = tid >> 4;                       // 0..15
    const long row    = (long)blockIdx.x * 16 + rloc;   // [0, B*L*L)
    const int  j      = (int)(row & (LL - 1));
    const long bi     = row >> 9;                       // b*L + i
    const int  b      = (int)(bi >> 9);
    const int  e0     = lane16 * 8;
    const long bj     = (long)b * LL + j;

    float p[8], gof[8], gif[8], oaf[8], iaf[8], bg[8], lw[8], lb[8];
    load8(pair    + row * DIM + e0, p);
    load8(go      + bi  * DIM + e0, gof);
    load8(gi      + bj  * DIM + e0, gif);
    load8(out_agg + bi  * DIM + e0, oaf);
    load8(in_agg  + bj  * DIM + e0, iaf);
    load8(b_g  + e0, bg);
    load8(ln_w + e0, lw);
    load8(ln_b + e0, lb);

    float x[8];
    float sum = 0.f, ss = 0.f;
#pragma unroll
    for (int c = 0; c < 8; ++c) {
        const float z    = gof[c] + gif[c] + bg[c];
        const float gate = 1.0f / (1.0f + __builtin_amdgcn_exp2f(z * -1.442695041f));
        const float u    = oaf[c] + iaf[c];
        const float xv   = p[c] + gate * (u - p[c]);
        x[c] = xv;
        sum += xv;
        ss  += xv * xv;
    }

    // reduce across the 16 lanes of this row (xor masks stay in-group)
#pragma unroll
    for (int m = 1; m < 16; m <<= 1) {
        sum += __shfl_xor(sum, m);
        ss  += __shfl_xor(ss,  m);
    }
    const float mu   = sum * (1.0f / DIM);
    const float var  = ss * (1.0f / DIM) - mu * mu;
    const float rstd = rsqrtf(var + EPSF);

    float y[8];
#pragma unroll
    for (int c = 0; c < 8; ++c)
        y[c] = (x[c] - mu) * rstd * lw[c] + lb[c];

    float* op = out + row * DIM + e0;
    reinterpret_cast<float4*>(op)[0] = make_float4(y[0], y[1], y[2], y[3]);
    reinterpret_cast<float4*>(op)[1] = make_float4(y[4], y[5], y[6], y[7]);
}

extern "C" void kernel_launch(void* const* d_in, const int* in_sizes, int n_in,
                              void* d_out, int out_size, void* d_ws, size_t ws_size,
                              hipStream_t stream) {
    const float* pair  = (const float*)d_in[0];
    const float* W_out = (const float*)d_in[1];
    const float* b_out = (const float*)d_in[2];
    const float* W_in  = (const float*)d_in[3];
    const float* b_in  = (const float*)d_in[4];
    const float* W_g   = (const float*)d_in[5];
    const float* b_g   = (const float*)d_in[6];
    const float* ln_w  = (const float*)d_in[7];
    const float* ln_b  = (const float*)d_in[8];
    float* out = (float*)d_out;

    float* agg   = (float*)d_ws;                     // 2*1024*128 f32 = 1 MB
    float* gpart = agg + 2 * BB * LL * DIM;          // 1 MB more

    agg_gemm_kernel<<<2 * BB * LL, DIM, 0, stream>>>(
        pair, W_out, b_out, W_in, b_in, W_g, agg, gpart);

    const int rows_per_block = 16;                   // 256 threads / 16 lanes
    fuse_ln_kernel<<<(BB * LL * LL) / rows_per_block, 256, 0, stream>>>(
        pair,
        agg,   agg   + BB * LL * DIM,
        gpart, gpart + BB * LL * DIM,
        b_g, ln_w, ln_b, out);
}